// Round 5
// baseline (970.914 us; speedup 1.0000x reference)
//
#include <hip/hip_runtime.h>
#include <hip/hip_bf16.h>

// Block_ViT on MI355X — round 17: new mfma4 = 128x128 tile, 4 waves (2x2),
// BK=64, 2 phases/K-tile with the proven mfma8 phase structure (ds_read ||
// stage -> bar -> lgkm0 -> setprio -> 16 MFMA -> counted vmcnt(4) -> bar),
// 64 KB LDS -> 2 blocks/CU for cross-block overlap. Deployed on ALL GEMMs with
// N>=128 && K>=128 (K-tail masked per-8-elem, so K=784 S-GEMM qualifies):
// K/V-proj (replaces mfma8: 800 vs 208 blocks), Qproj, S (+fused IN stats),
// per-head PV (K=3840 single-GEMM reverted: it was R16's 84us regression),
// Wo, FFN1, FFN2. mfma2 remains for the C=64 branch only. mfma8 removed.
// B=4, N=784, H=4, Cs={64,128,256,512}, KV=960, NT=3136. fp32 in/out.

using bf16 = __hip_bfloat16;
typedef __attribute__((ext_vector_type(8))) short short8;   // 8 bf16 (4 VGPRs)
typedef __attribute__((ext_vector_type(4))) float f32x4;    // MFMA acc

__device__ inline float bf2f(unsigned short u) {
    return __uint_as_float(((unsigned int)u) << 16);
}
__device__ inline unsigned short f2b(float f) {            // RTNE fp32->bf16
    unsigned int u = __float_as_uint(f);
    return (unsigned short)((u + 0x7fffu + ((u >> 16) & 1u)) >> 16);
}
__device__ inline float ld1f(const float* p) { return *p; }
__device__ inline float ld1f(const bf16* p) { return bf2f(*(const unsigned short*)p); }
__device__ inline void st1(float* p, float v) { *p = v; }
__device__ inline void st1(bf16* p, float v) { *((unsigned short*)p) = f2b(v); }
__device__ inline float4 ld4f(const bf16* p) {
    ushort4 u = *(const ushort4*)p;
    return make_float4(bf2f(u.x), bf2f(u.y), bf2f(u.z), bf2f(u.w));
}

// async global->LDS, 16 B per lane; LDS dest = wave-uniform base + lane*16
__device__ __forceinline__ void cp16(const void* g, void* l) {
    __builtin_amdgcn_global_load_lds(
        (const __attribute__((address_space(1))) void*)g,
        (__attribute__((address_space(3))) void*)l, 16, 0, 0);
}

// ---- block reductions (256 threads = 4 waves) ----
__device__ inline float blockSum256(float v, float* red) {
    #pragma unroll
    for (int o = 32; o > 0; o >>= 1) v += __shfl_down(v, o);
    int t = threadIdx.x;
    if ((t & 63) == 0) red[t >> 6] = v;
    __syncthreads();
    float r = red[0] + red[1] + red[2] + red[3];
    __syncthreads();
    return r;
}
__device__ inline float blockMax256(float v, float* red) {
    #pragma unroll
    for (int o = 32; o > 0; o >>= 1) v = fmaxf(v, __shfl_down(v, o));
    int t = threadIdx.x;
    if ((t & 63) == 0) red[t >> 6] = v;
    __syncthreads();
    float r = fmaxf(fmaxf(red[0], red[1]), fmaxf(red[2], red[3]));
    __syncthreads();
    return r;
}

// ---- fp32 -> bf16 weight conversion + optional stat zeroing ----
struct Cvt4 {
    const float* s[4];
    unsigned short* d[4];
    long n[4];
    float* z32;           // if non-null: zero 32 floats (IN stats accumulator)
};
__global__ __launch_bounds__(256)
void cvt_kernel(Cvt4 a) {
    if (a.z32 && blockIdx.x == 0 && threadIdx.x < 32) a.z32[threadIdx.x] = 0.f;
    long tid = (long)blockIdx.x * 256 + threadIdx.x;
    long stride = (long)gridDim.x * 256;
    for (int g = 0; g < 4; g++) {
        const float* s = a.s[g];
        if (!s) continue;
        unsigned short* d = a.d[g];
        long n = a.n[g];
        for (long i = tid * 4; i < n; i += stride * 4) {
            float4 v = *(const float4*)(s + i);
            *(ushort4*)(d + i) = make_ushort4(f2b(v.x), f2b(v.y), f2b(v.z), f2b(v.w));
        }
    }
}

// ==== mfma4: 128x128 tile, 4 waves (2Mx2N), BK=64, 2 phases per K-tile ====
// REQUIRES K >= 128, K % 8 == 0 (K%64 tail handled via masked slow staging).
// LDS per operand: [2 slots][2 k-halves][128 rows][32 shorts] (64 B rows),
// 64 KB total -> 2 blocks/CU. Swizzle hash h(r) = (r>>1)&3 (R13-proven):
// phys 16B-slot = logical ^ h(row); fast staging pre-swizzles the GLOBAL
// source column; fragment read applies h on the slot. Per phase:
//   {8 ds_read_b128 (half frags) || 4 cp16 (next-tile A+B half) -> s_barrier
//    -> lgkmcnt(0)+sched_barrier -> setprio(1) 16 MFMA setprio(0)
//    -> s_waitcnt vmcnt(4) counted -> s_barrier}
// vmcnt(4) at each phase end lands exactly the half the NEXT phase reads
// while keeping the 4 just-issued loads in flight. Slow paths self-drain.
template <class CT, class RT, bool TO>
__global__ __launch_bounds__(256, 2)
void mfma4(const bf16* __restrict__ A, long Ah, long Ab, int lda,
           const bf16* __restrict__ B, long Bh, long Bb, int ldb,
           CT* __restrict__ Cp, long Ch, long Cb, int ldc,
           const float* __restrict__ bias, const RT* __restrict__ res,
           int M, int N, int K, float alpha, int dogelu,
           float* __restrict__ stat) {
    __shared__ short Asl[2][2][128][32];
    __shared__ short Bsl[2][2][128][32];
    int z = blockIdx.z;
    A += (long)(z & 3) * Ah + (long)(z >> 2) * Ab;
    B += (long)(z & 3) * Bh + (long)(z >> 2) * Bb;
    Cp += (long)(z & 3) * Ch + (long)(z >> 2) * Cb;
    int m0 = blockIdx.y * 128, n0 = blockIdx.x * 128;
    int t = threadIdx.x, lane = t & 63, wv = t >> 6;   // wv 0..3
    int col = lane & 15, quad = lane >> 4;
    int wm = wv >> 1, wn = wv & 1;                     // 2(M) x 2(N)
    f32x4 acc[4][4];
    #pragma unroll
    for (int i = 0; i < 4; i++)
        #pragma unroll
        for (int j = 0; j < 4; j++) acc[i][j] = (f32x4){0.f, 0.f, 0.f, 0.f};

    const bool fA = (m0 + 128 <= M);
    const bool fB = (n0 + 128 <= N);
    // fast staging: lane -> (row R0 + lane>>2, phys slot lane&3); source col
    // pre-swizzled by h(row) = (lane>>3)&3 (R0 multiple of 16)
    int srow = lane >> 2;
    int scol = ((lane & 3) ^ ((lane >> 3) & 3)) << 3;
    // fragment read: row = 16m + col -> h(row) = (col>>1)&3
    int rslot = (quad ^ ((col >> 1) & 3)) << 3;

    auto stageA = [&](int s2, int kt, int kh) {
        int k0 = kt * 64 + kh * 32;
        if (fA && k0 + 32 <= K) {
            #pragma unroll
            for (int r = 0; r < 2; r++) {
                int R0 = (r * 4 + wv) * 16;
                cp16(A + (long)(m0 + R0 + srow) * lda + k0 + scol,
                     &Asl[s2][kh][R0][0]);
            }
        } else {
            #pragma unroll
            for (int r = 0; r < 2; r++) {
                int idx = r * 256 + t;
                int row = idx >> 2, sl = idx & 3;
                int f2 = (row >> 1) & 3;
                short8 v = {};
                if (m0 + row < M && k0 + sl * 8 < K)   // K%8==0 at all call sites
                    v = *(const short8*)(A + (long)(m0 + row) * lda + k0 + sl * 8);
                *(short8*)&Asl[s2][kh][row][(sl ^ f2) * 8] = v;
            }
            asm volatile("s_waitcnt lgkmcnt(0)" ::: "memory");
        }
    };
    auto stageB = [&](int s2, int kt, int kh) {
        int k0 = kt * 64 + kh * 32;
        if (fB && k0 + 32 <= K) {
            #pragma unroll
            for (int r = 0; r < 2; r++) {
                int R0 = (r * 4 + wv) * 16;
                cp16(B + (long)(n0 + R0 + srow) * ldb + k0 + scol,
                     &Bsl[s2][kh][R0][0]);
            }
        } else {
            #pragma unroll
            for (int r = 0; r < 2; r++) {
                int idx = r * 256 + t;
                int row = idx >> 2, sl = idx & 3;
                int f2 = (row >> 1) & 3;
                short8 v = {};
                if (n0 + row < N && k0 + sl * 8 < K)
                    v = *(const short8*)(B + (long)(n0 + row) * ldb + k0 + sl * 8);
                *(short8*)&Bsl[s2][kh][row][(sl ^ f2) * 8] = v;
            }
            asm volatile("s_waitcnt lgkmcnt(0)" ::: "memory");
        }
    };

    int nk = (K + 63) >> 6;
    stageA(0, 0, 0); stageB(0, 0, 0); stageA(0, 0, 1); stageB(0, 0, 1);
    __syncthreads();

    for (int kt = 0; kt < nk; kt++) {
        int cur = kt & 1, nxt = cur ^ 1;
        bool st = (kt + 1 < nk);
        short8 af[4], bf4[4];
        // ---------- phase 0: k-half 0 ----------
        #pragma unroll
        for (int mi = 0; mi < 4; mi++)
            af[mi] = *(const short8*)&Asl[cur][0][wm * 64 + mi * 16 + col][rslot];
        #pragma unroll
        for (int ni = 0; ni < 4; ni++)
            bf4[ni] = *(const short8*)&Bsl[cur][0][wn * 64 + ni * 16 + col][rslot];
        if (st) { stageA(nxt, kt + 1, 0); stageB(nxt, kt + 1, 0); }
        __builtin_amdgcn_s_barrier();
        asm volatile("s_waitcnt lgkmcnt(0)" ::: "memory");
        __builtin_amdgcn_sched_barrier(0);
        __builtin_amdgcn_s_setprio(1);
        #pragma unroll
        for (int mi = 0; mi < 4; mi++)
            #pragma unroll
            for (int ni = 0; ni < 4; ni++)
                acc[mi][ni] = __builtin_amdgcn_mfma_f32_16x16x32_bf16(
                    af[mi], bf4[ni], acc[mi][ni], 0, 0, 0);
        __builtin_amdgcn_s_setprio(0);
        if (st) {
            if (fA && fB)      asm volatile("s_waitcnt vmcnt(4)" ::: "memory");
            else if (fA || fB) asm volatile("s_waitcnt vmcnt(2)" ::: "memory");
        } else {
            asm volatile("s_waitcnt vmcnt(0)" ::: "memory");
        }
        __builtin_amdgcn_s_barrier();
        // ---------- phase 1: k-half 1 ----------
        #pragma unroll
        for (int mi = 0; mi < 4; mi++)
            af[mi] = *(const short8*)&Asl[cur][1][wm * 64 + mi * 16 + col][rslot];
        #pragma unroll
        for (int ni = 0; ni < 4; ni++)
            bf4[ni] = *(const short8*)&Bsl[cur][1][wn * 64 + ni * 16 + col][rslot];
        if (st) { stageA(nxt, kt + 1, 1); stageB(nxt, kt + 1, 1); }
        __builtin_amdgcn_s_barrier();
        asm volatile("s_waitcnt lgkmcnt(0)" ::: "memory");
        __builtin_amdgcn_sched_barrier(0);
        __builtin_amdgcn_s_setprio(1);
        #pragma unroll
        for (int mi = 0; mi < 4; mi++)
            #pragma unroll
            for (int ni = 0; ni < 4; ni++)
                acc[mi][ni] = __builtin_amdgcn_mfma_f32_16x16x32_bf16(
                    af[mi], bf4[ni], acc[mi][ni], 0, 0, 0);
        __builtin_amdgcn_s_setprio(0);
        if (st) {
            if (fA && fB)      asm volatile("s_waitcnt vmcnt(4)" ::: "memory");
            else if (fA || fB) asm volatile("s_waitcnt vmcnt(2)" ::: "memory");
        }
        __builtin_amdgcn_s_barrier();
    }
    // epilogue — C/D layout: col=lane&15, row=quad*4+reg [m89/m91]
    float psum = 0.f, psq = 0.f;
    #pragma unroll
    for (int mi = 0; mi < 4; mi++) {
        int gmB = m0 + wm * 64 + mi * 16 + quad * 4;
        #pragma unroll
        for (int ni = 0; ni < 4; ni++) {
            int gn = n0 + wn * 64 + ni * 16 + col;
            if constexpr (TO) {
                if (gmB < M && gn < N) {
                    ushort4 w = make_ushort4(f2b(acc[mi][ni][0] * alpha),
                                             f2b(acc[mi][ni][1] * alpha),
                                             f2b(acc[mi][ni][2] * alpha),
                                             f2b(acc[mi][ni][3] * alpha));
                    *(ushort4*)((unsigned short*)Cp + (long)gn * ldc + gmB) = w;
                }
            } else {
                if (gn < N) {
                    float bz = bias ? bias[gn] : 0.f;
                    #pragma unroll
                    for (int r = 0; r < 4; r++) {
                        int gm = gmB + r;
                        if (gm < M) {
                            float v = acc[mi][ni][r] * alpha + bz;
                            if (dogelu) v = 0.5f * v * (1.f + erff(v * 0.70710678118f));
                            if (res) v += ld1f(res + (long)gm * ldc + gn);
                            st1(Cp + (long)gm * ldc + gn, v);
                            psum += v; psq += v * v;
                        }
                    }
                }
            }
        }
    }
    if (stat) {   // fused InstanceNorm partial stats, one atomicAdd pair/block
        __syncthreads();
        #pragma unroll
        for (int o = 32; o > 0; o >>= 1) {
            psum += __shfl_down(psum, o);
            psq  += __shfl_down(psq, o);
        }
        float* red = (float*)Asl;
        if ((t & 63) == 0) { red[wv] = psum; red[4 + wv] = psq; }
        __syncthreads();
        if (t == 0) {
            atomicAdd(&stat[2 * z],     red[0] + red[1] + red[2] + red[3]);
            atomicAdd(&stat[2 * z + 1], red[4] + red[5] + red[6] + red[7]);
        }
    }
}

// ==== mfma2 (R13 form) + optional fused sum/sumsq stats — C=64 branch only ====
template <int TM, int TN, class CT, class RT, bool TO>
__global__ __launch_bounds__(256)
void mfma2(const bf16* __restrict__ A, long Ah, long Ab, int lda,
           const bf16* __restrict__ B, long Bh, long Bb, int ldb,
           CT* __restrict__ Cp, long Ch, long Cb, int ldc,
           const float* __restrict__ bias, const RT* __restrict__ res,
           int M, int N, int K, float alpha, int dogelu,
           float* __restrict__ stat) {
    constexpr int MI = TM / 32, NI = TN / 32;
    __shared__ short As[2][TM * 32];
    __shared__ short Bs[2][TN * 32];
    int z = blockIdx.z;
    A += (long)(z & 3) * Ah + (long)(z >> 2) * Ab;
    B += (long)(z & 3) * Bh + (long)(z >> 2) * Bb;
    Cp += (long)(z & 3) * Ch + (long)(z >> 2) * Cb;
    int m0 = blockIdx.y * TM, n0 = blockIdx.x * TN;
    int t = threadIdx.x, lane = t & 63, wv = t >> 6;
    int col = lane & 15, quad = lane >> 4;
    int wm = wv >> 1, wn = wv & 1;
    f32x4 acc[MI][NI];
    #pragma unroll
    for (int i = 0; i < MI; i++)
        #pragma unroll
        for (int j = 0; j < NI; j++) acc[i][j] = (f32x4){0.f, 0.f, 0.f, 0.f};

    const bool fastblk = (m0 + TM <= M) && (n0 + TN <= N);
    int lrow = lane >> 2;
    int lcol = ((lane & 3) ^ ((lane >> 3) & 3)) << 3;
    int sr = t >> 2;
    int swz = ((t & 3) ^ ((t >> 3) & 3)) << 3;
    int sdst = (t & 3) << 3;
    int rdslot = (quad ^ ((col >> 1) & 3)) << 3;

    auto stage = [&](int b, int k0) {
        if (fastblk && (k0 + 32 <= K)) {
            #pragma unroll
            for (int u = 0; u < TM / 64; u++) {
                int c = wv + 4 * u;
                int r = c * 16 + lrow;
                cp16(A + (long)(m0 + r) * lda + k0 + lcol, &As[b][c * 512]);
            }
            #pragma unroll
            for (int u = 0; u < TN / 64; u++) {
                int c = wv + 4 * u;
                int r = c * 16 + lrow;
                cp16(B + (long)(n0 + r) * ldb + k0 + lcol, &Bs[b][c * 512]);
            }
        } else {
            #pragma unroll
            for (int u = 0; u < TM / 64; u++) {
                int r = sr + u * 64;
                float4 v = make_float4(0.f, 0.f, 0.f, 0.f);
                if (m0 + r < M && k0 + swz < K)
                    v = *(const float4*)(A + (long)(m0 + r) * lda + k0 + swz);
                *(float4*)&As[b][r * 32 + sdst] = v;
            }
            #pragma unroll
            for (int u = 0; u < TN / 64; u++) {
                int r = sr + u * 64;
                float4 v = make_float4(0.f, 0.f, 0.f, 0.f);
                if (n0 + r < N && k0 + swz < K)
                    v = *(const float4*)(B + (long)(n0 + r) * ldb + k0 + swz);
                *(float4*)&Bs[b][r * 32 + sdst] = v;
            }
        }
    };

    int nk = (K + 31) >> 5;
    stage(0, 0);
    __syncthreads();
    int cur = 0;
    for (int s = 0; s < nk; s++) {
        if (s + 1 < nk) stage(cur ^ 1, (s + 1) * 32);
        short8 af[MI], bfr[NI];
        #pragma unroll
        for (int mi = 0; mi < MI; mi++)
            af[mi] = *(const short8*)&As[cur][(wm * (TM / 2) + mi * 16 + col) * 32 + rdslot];
        #pragma unroll
        for (int ni = 0; ni < NI; ni++)
            bfr[ni] = *(const short8*)&Bs[cur][(wn * (TN / 2) + ni * 16 + col) * 32 + rdslot];
        #pragma unroll
        for (int mi = 0; mi < MI; mi++)
            #pragma unroll
            for (int ni = 0; ni < NI; ni++)
                acc[mi][ni] = __builtin_amdgcn_mfma_f32_16x16x32_bf16(
                    af[mi], bfr[ni], acc[mi][ni], 0, 0, 0);
        if (s + 1 < nk) __syncthreads();
        cur ^= 1;
    }
    float psum = 0.f, psq = 0.f;
    #pragma unroll
    for (int mi = 0; mi < MI; mi++) {
        int gmB = m0 + wm * (TM / 2) + mi * 16 + quad * 4;
        #pragma unroll
        for (int ni = 0; ni < NI; ni++) {
            int gn = n0 + wn * (TN / 2) + ni * 16 + col;
            if constexpr (TO) {
                if (gmB < M && gn < N) {
                    ushort4 w = make_ushort4(f2b(acc[mi][ni][0] * alpha),
                                             f2b(acc[mi][ni][1] * alpha),
                                             f2b(acc[mi][ni][2] * alpha),
                                             f2b(acc[mi][ni][3] * alpha));
                    *(ushort4*)((unsigned short*)Cp + (long)gn * ldc + gmB) = w;
                }
            } else {
                if (gn < N) {
                    float bz = bias ? bias[gn] : 0.f;
                    #pragma unroll
                    for (int r = 0; r < 4; r++) {
                        int gm = gmB + r;
                        if (gm < M) {
                            float v = acc[mi][ni][r] * alpha + bz;
                            if (dogelu) v = 0.5f * v * (1.f + erff(v * 0.70710678118f));
                            if (res) v += ld1f(res + (long)gm * ldc + gn);
                            st1(Cp + (long)gm * ldc + gn, v);
                            psum += v; psq += v * v;
                        }
                    }
                }
            }
        }
    }
    if (stat) {
        __syncthreads();
        #pragma unroll
        for (int o = 32; o > 0; o >>= 1) {
            psum += __shfl_down(psum, o);
            psq  += __shfl_down(psq, o);
        }
        float* red = (float*)As;
        if ((t & 63) == 0) { red[wv] = psum; red[4 + wv] = psq; }
        __syncthreads();
        if (t == 0) {
            atomicAdd(&stat[2 * z],     red[0] + red[1] + red[2] + red[3]);
            atomicAdd(&stat[2 * z + 1], red[4] + red[5] + red[6] + red[7]);
        }
    }
}

// ---- merged LayerNorms: concat-LN (ea) + 4 branch first-LNs, one emb read ----
struct LNA {
    const float* e[4];
    const float* ag[4];
    const float* ab[4];
    const float* cg;
    const float* cbb;
    bf16* y[4];
    bf16* ea;
};
__global__ __launch_bounds__(256)
void ln_all_kernel(LNA a) {
    __shared__ float x[960];
    __shared__ float red[4];
    long row = blockIdx.x;
    int t = threadIdx.x;
    const int off[5] = {0, 64, 192, 448, 960};
    {
        const float* p1 = a.e[0] + row * 64;
        const float* p2 = a.e[1] + row * 128;
        const float* p3 = a.e[2] + row * 256;
        const float* p4 = a.e[3] + row * 512;
        if (t < 64) x[t] = p1[t];
        for (int i = t; i < 128; i += 256) x[64 + i]  = p2[i];
        for (int i = t; i < 256; i += 256) x[192 + i] = p3[i];
        for (int i = t; i < 512; i += 256) x[448 + i] = p4[i];
    }
    __syncthreads();
    float ssum[4], ssq[4];
    #pragma unroll
    for (int br = 0; br < 4; br++) {
        float s = 0.f, q = 0.f;
        for (int i = off[br] + t; i < off[br + 1]; i += 256) {
            float v = x[i]; s += v; q += v * v;
        }
        ssum[br] = blockSum256(s, red);
        ssq[br]  = blockSum256(q, red);
    }
    float S1 = ssum[0] + ssum[1] + ssum[2] + ssum[3];
    float S2 = ssq[0] + ssq[1] + ssq[2] + ssq[3];
    float muA = S1 * (1.f / 960.f);
    float rA = rsqrtf(S2 * (1.f / 960.f) - muA * muA + 1e-6f);
    for (int i = t; i < 960; i += 256)
        st1(a.ea + row * 960 + i, (x[i] - muA) * rA * a.cg[i] + a.cbb[i]);
    #pragma unroll
    for (int br = 0; br < 4; br++) {
        int C = off[br + 1] - off[br];
        float mu = ssum[br] / C;
        float rr = rsqrtf(ssq[br] / C - mu * mu + 1e-6f);
        const float* g = a.ag[br];
        const float* b = a.ab[br];
        bf16* y = a.y[br] + row * C;
        for (int i = t; i < C; i += 256)
            st1(y + i, (x[off[br] + i] - mu) * rr * g[i] + b[i]);
    }
}

// ---- row LayerNorm (bf16 in) -> bf16 ----
__global__ __launch_bounds__(256)
void ln_rows_kernel(const bf16* __restrict__ X, const float* __restrict__ g,
                    const float* __restrict__ b, bf16* __restrict__ Y, int C) {
    __shared__ float x[512];
    __shared__ float red[4];
    long row = blockIdx.x;
    int t = threadIdx.x;
    const bf16* xr = X + row * C;
    float s = 0.f, q = 0.f;
    for (int i = t; i < C; i += 256) { float v = ld1f(xr + i); x[i] = v; s += v; q += v * v; }
    float S1 = blockSum256(s, red), S2 = blockSum256(q, red);
    float mu = S1 / C;
    float r = rsqrtf(S2 / C - mu * mu + 1e-6f);
    for (int i = t; i < C; i += 256)
        st1(Y + row * C + i, (x[i] - mu) * r * g[i] + b[i]);
}

// ---- ctx head-sum: ctx[i] = 0.25*sum_h tmp[h][i] ----
__global__ __launch_bounds__(256)
void ctx_sum_kernel(const bf16* __restrict__ tmp, bf16* __restrict__ ctx, long NTC) {
    long i = ((long)blockIdx.x * 256 + threadIdx.x) * 4;
    float4 a = ld4f(tmp + i);
    float4 b = ld4f(tmp + NTC + i);
    float4 c = ld4f(tmp + 2 * NTC + i);
    float4 d = ld4f(tmp + 3 * NTC + i);
    ushort4 o = make_ushort4(f2b((a.x + b.x + c.x + d.x) * 0.25f),
                             f2b((a.y + b.y + c.y + d.y) * 0.25f),
                             f2b((a.z + b.z + c.z + d.z) * 0.25f),
                             f2b((a.w + b.w + c.w + d.w) * 0.25f));
    *(ushort4*)(ctx + i) = o;
}

// ---- softmax over last dim (960) of S2[b][C][4*960]; rstd from fused stats ----
__global__ __launch_bounds__(256)
void softmax_kernel(bf16* __restrict__ S, const float* __restrict__ stat, int C) {
    __shared__ float x[960];
    __shared__ float red[4];
    long r = blockIdx.x;
    int t = threadIdx.x;
    int z = (int)(r / C);           // z = 4h + b? (z&3=h layout: z = h + 4b NO — z&3=h)
    int d = (int)(r % C);
    float n = 960.f * (float)C;
    float s0 = stat[2 * z], q0 = stat[2 * z + 1];
    float mu = s0 / n;
    float rs = rsqrtf(q0 / n - mu * mu + 1e-5f);
    // stats were accumulated at z with z&3=h, z>>2=b; decode consistently:
    int h = z & 3, b = z >> 2;
    bf16* row = S + (long)b * C * 3840 + (long)d * 3840 + h * 960;
    float mx = -3.4e38f;
    for (int i = t; i < 960; i += 256) {
        float v = ld1f(row + i) * rs; x[i] = v; mx = fmaxf(mx, v);
    }
    float M = blockMax256(mx, red);
    float s = 0.f;
    for (int i = t; i < 960; i += 256) { float e = __expf(x[i] - M); x[i] = e; s += e; }
    float Ssum = blockSum256(s, red);
    float inv = 1.f / Ssum;
    for (int i = t; i < 960; i += 256) st1(row + i, x[i] * inv);
}

extern "C" void kernel_launch(void* const* d_in, const int* in_sizes, int n_in,
                              void* d_out, int out_size, void* d_ws, size_t ws_size,
                              hipStream_t stream) {
    (void)in_sizes; (void)n_in; (void)out_size; (void)ws_size;
    const int Cs[4] = {64, 128, 256, 512};
    const float *emb[4], *ang[4], *anb[4], *Wq[4], *Wo[4], *fng[4], *fnb[4], *w1[4], *b1[4], *w2[4], *b2[4];
    for (int i = 0; i < 4; i++) {
        const int base = i * 11;
        emb[i] = (const float*)d_in[base + 0];
        ang[i] = (const float*)d_in[base + 1];
        anb[i] = (const float*)d_in[base + 2];
        Wq[i]  = (const float*)d_in[base + 3];
        Wo[i]  = (const float*)d_in[base + 4];
        fng[i] = (const float*)d_in[base + 5];
        fnb[i] = (const float*)d_in[base + 6];
        w1[i]  = (const float*)d_in[base + 7];
        b1[i]  = (const float*)d_in[base + 8];
        w2[i]  = (const float*)d_in[base + 9];
        b2[i]  = (const float*)d_in[base + 10];
    }
    const float* anAg = (const float*)d_in[44];
    const float* anAb = (const float*)d_in[45];
    const float* Wk   = (const float*)d_in[46];
    const float* Wv   = (const float*)d_in[47];

    const int NT = 3136;
    char* wsb = (char*)d_ws;
    bf16*   ea    = (bf16*)(wsb);                    // [3136,960]
    bf16*   KT    = (bf16*)(wsb + 6021120);          // [4][960][3136]
    bf16*   Vb2   = (bf16*)(wsb + 30105600);         // [3136][3840] head-concat V
    bf16*   Qb    = (bf16*)(wsb + 54190080);         // QT / per-head tmp / hid
    bf16*   Sb    = (bf16*)(wsb + 67035136);         // S2 [b][C][3840]; wk/wv early
    bf16*   cxall = (bf16*)(wsb + 82763776);         // first-LN out, all branches
    bf16*   cxb   = (bf16*)(wsb + 88784896);         // ctx / post-res LN
    bf16*   xb    = (bf16*)(wsb + 91996160);         // residual
    bf16*   wtb   = (bf16*)(wsb + 95207424);         // per-branch weights, reused
    float*  statb = (float*)(wsb + 102023168);       // [32] IN sum/sumsq per z

    bf16* wkb = Sb;                 // Sb region free until branch-0 scores
    bf16* wvb = Sb + 3686400;
    const long cxoff[4] = {0, 64L * NT, 192L * NT, 448L * NT};

    float* out = (float*)d_out;
    const long ooff[4] = {0, 200704, 602112, 1404928};
    const float scale = 0.03227486121f;  // 1/sqrt(960)

    {
        Cvt4 a;
        a.s[0] = Wk; a.d[0] = (unsigned short*)wkb; a.n[0] = 3686400;
        a.s[1] = Wv; a.d[1] = (unsigned short*)wvb; a.n[1] = 3686400;
        a.s[2] = nullptr; a.s[3] = nullptr; a.d[2] = a.d[3] = nullptr; a.n[2] = a.n[3] = 0;
        a.z32 = nullptr;
        cvt_kernel<<<512, 256, 0, stream>>>(a);
    }
    {
        LNA a;
        for (int i = 0; i < 4; i++) {
            a.e[i] = emb[i]; a.ag[i] = ang[i]; a.ab[i] = anb[i];
            a.y[i] = cxall + cxoff[i];
        }
        a.cg = anAg; a.cbb = anAb; a.ea = ea;
        ln_all_kernel<<<3136, 256, 0, stream>>>(a);
    }
    // KT[h] = (ea @ Wk[h]^T)^T ; V head-concat Vb2[n][h*960+j]  (mfma4)
    mfma4<bf16, float, true><<<dim3(8, 25, 4), 256, 0, stream>>>(
        ea, 0, 0, 960, wkb, 921600, 0, 960, KT, 3010560, 0, NT,
        nullptr, (const float*)nullptr, NT, 960, 960, 1.f, 0, nullptr);
    mfma4<bf16, float, false><<<dim3(8, 25, 4), 256, 0, stream>>>(
        ea, 0, 0, 960, wvb, 921600, 0, 960, Vb2, 960, 0, 3840,
        nullptr, (const float*)nullptr, NT, 960, 960, 1.f, 0, nullptr);

    for (int i = 0; i < 4; i++) {
        const int C = Cs[i];
        const long C2 = (long)C * C;
        bf16* wqb = wtb;
        bf16* wob = wtb + 4 * C2;
        bf16* w1b = wtb + 5 * C2;
        bf16* w2b = wtb + 9 * C2;
        {
            Cvt4 a;
            a.s[0] = Wq[i]; a.d[0] = (unsigned short*)wqb; a.n[0] = 4 * C2;
            a.s[1] = Wo[i]; a.d[1] = (unsigned short*)wob; a.n[1] = C2;
            a.s[2] = w1[i]; a.d[2] = (unsigned short*)w1b; a.n[2] = 4 * C2;
            a.s[3] = w2[i]; a.d[3] = (unsigned short*)w2b; a.n[3] = 4 * C2;
            a.z32 = statb;                 // zero IN stats for this branch
            cvt_kernel<<<512, 256, 0, stream>>>(a);
        }
        if (C >= 128) {
            // QT[h] = (cx @ Wq[h]^T)^T
            mfma4<bf16, float, true><<<dim3(C / 128, 25, 4), 256, 0, stream>>>(
                cxall + cxoff[i], 0, 0, C, wqb, C2, 0, C, Qb, (long)C * NT, 0, NT,
                nullptr, (const float*)nullptr, NT, C, C, 1.f, 0, nullptr);
            // S2[b][d][h*960+j] = scale * QT @ KT^T   (K=784, tail-masked) + stats
            mfma4<bf16, float, false><<<dim3(8, C / 128, 16), 256, 0, stream>>>(
                Qb, (long)C * NT, 784, NT, KT, 3010560, 784, NT,
                Sb, 960, (long)C * 3840, 3840,
                nullptr, (const float*)nullptr, C, 960, 784, scale, 0, statb);
        } else {
            mfma2<64, 64, bf16, float, true><<<dim3(1, 49, 4), 256, 0, stream>>>(
                cxall + cxoff[i], 0, 0, C, wqb, C2, 0, C, Qb, (long)C * NT, 0, NT,
                nullptr, (const float*)nullptr, NT, C, C, 1.f, 0, nullptr);
            mfma2<64, 64, bf16, float, false><<<dim3(15, 1, 16), 256, 0, stream>>>(
                Qb, (long)C * NT, 784, NT, KT, 3010560, 784, NT,
                Sb, 960, (long)C * 3840, 3840,
                nullptr, (const float*)nullptr, C, 960, 784, scale, 0, statb);
        }
        softmax_kernel<<<16 * C, 256, 0, stream>>>(Sb, statb, C);
        // tmp[h] = V-slab @ S[z]^T  (per-head K=960) -> ctx_sum
        if (C >= 128)
            mfma4<bf16, float, false><<<dim3(C / 128, 7, 16), 256, 0, stream>>>(
                Vb2, 960, 784L * 3840, 3840, Sb, 960, (long)C * 3840, 3840,
                Qb, (long)NT * C, 784L * C, C,
                nullptr, (const float*)nullptr, 784, C, 960, 1.f, 0, nullptr);
        else
            mfma2<64, 64, bf16, float, false><<<dim3(1, 13, 16), 256, 0, stream>>>(
                Vb2, 960, 784L * 3840, 3840, Sb, 960, (long)C * 3840, 3840,
                Qb, (long)NT * C, 784L * C, C,
                nullptr, (const float*)nullptr, 784, C, 960, 1.f, 0, nullptr);
        ctx_sum_kernel<<<(int)(((long)NT * C) / 1024), 256, 0, stream>>>(
            Qb, cxb, (long)NT * C);
        // x = emb + ctx @ Wo^T  -> bf16
        if (C >= 128)
            mfma4<bf16, float, false><<<dim3(C / 128, 25, 1), 256, 0, stream>>>(
                cxb, 0, 0, C, wob, 0, 0, C, xb, 0, 0, C,
                nullptr, emb[i], NT, C, C, 1.f, 0, nullptr);
        else
            mfma2<64, 64, bf16, float, false><<<dim3(1, 49, 1), 256, 0, stream>>>(
                cxb, 0, 0, C, wob, 0, 0, C, xb, 0, 0, C,
                nullptr, emb[i], NT, C, C, 1.f, 0, nullptr);
        ln_rows_kernel<<<NT, 256, 0, stream>>>(xb, fng[i], fnb[i], cxb, C);
        // hid = gelu(lnx @ w1^T + b1) -> bf16
        if (C >= 128)
            mfma4<bf16, float, false><<<dim3(4 * C / 128, 25, 1), 256, 0, stream>>>(
                cxb, 0, 0, C, w1b, 0, 0, C, Qb, 0, 0, 4 * C,
                b1[i], (const float*)nullptr, NT, 4 * C, C, 1.f, 1, nullptr);
        else
            mfma2<64, 64, bf16, float, false><<<dim3(4, 49, 1), 256, 0, stream>>>(
                cxb, 0, 0, C, w1b, 0, 0, C, Qb, 0, 0, 4 * C,
                b1[i], (const float*)nullptr, NT, 4 * C, C, 1.f, 1, nullptr);
        // out = x + hid @ w2^T + b2  (fp32 store to d_out)
        if (C >= 128)
            mfma4<float, bf16, false><<<dim3(C / 128, 25, 1), 256, 0, stream>>>(
                Qb, 0, 0, 4 * C, w2b, 0, 0, 4 * C, out + ooff[i], 0, 0, C,
                b2[i], xb, NT, C, 4 * C, 1.f, 0, nullptr);
        else
            mfma2<64, 64, float, bf16, false><<<dim3(1, 49, 1), 256, 0, stream>>>(
                Qb, 0, 0, 4 * C, w2b, 0, 0, 4 * C, out + ooff[i], 0, 0, C,
                b2[i], xb, NT, C, 4 * C, 1.f, 0, nullptr);
    }
}

// Round 6
// 906.810 us; speedup vs baseline: 1.0707x; 1.0707x over previous
//
#include <hip/hip_runtime.h>
#include <hip/hip_bf16.h>

// Block_ViT on MI355X — round 18: memory-locality round.
// R17 post-mortem: all schedules pin at ~300 TF because staging traffic
// (393 MB virtual/dispatch = 5.2 TB/s effective) saturates L2/L3 supply;
// FETCH 51.8 MB vs 13.4 MB unique = ~8x XCD refetch of A-panels.
// (a) mfma4 gains an XCD-chunked bijective block remap (m204): each XCD gets
//     a contiguous m-major chunk of tiles -> A-panels L2-resident per XCD.
// (b) Mpad/Npad staging bounds kill ALL M/N-tail slow paths: pad rows read
//     garbage from allocated ws, lanes are store-masked (stats only sum
//     stored values). K-tails keep the masked slow path.
// (c) K/V-proj head-batched: z=1, N=3840 (Wk already [3840][960] contiguous),
//     M padded 3136->3328, grids 30x26.
// B=4, N=784, H=4, Cs={64,128,256,512}, KV=960, NT=3136. fp32 in/out.

using bf16 = __hip_bfloat16;
typedef __attribute__((ext_vector_type(8))) short short8;   // 8 bf16 (4 VGPRs)
typedef __attribute__((ext_vector_type(4))) float f32x4;    // MFMA acc

__device__ inline float bf2f(unsigned short u) {
    return __uint_as_float(((unsigned int)u) << 16);
}
__device__ inline unsigned short f2b(float f) {            // RTNE fp32->bf16
    unsigned int u = __float_as_uint(f);
    return (unsigned short)((u + 0x7fffu + ((u >> 16) & 1u)) >> 16);
}
__device__ inline float ld1f(const float* p) { return *p; }
__device__ inline float ld1f(const bf16* p) { return bf2f(*(const unsigned short*)p); }
__device__ inline void st1(float* p, float v) { *p = v; }
__device__ inline void st1(bf16* p, float v) { *((unsigned short*)p) = f2b(v); }
__device__ inline float4 ld4f(const bf16* p) {
    ushort4 u = *(const ushort4*)p;
    return make_float4(bf2f(u.x), bf2f(u.y), bf2f(u.z), bf2f(u.w));
}

// async global->LDS, 16 B per lane; LDS dest = wave-uniform base + lane*16
__device__ __forceinline__ void cp16(const void* g, void* l) {
    __builtin_amdgcn_global_load_lds(
        (const __attribute__((address_space(1))) void*)g,
        (__attribute__((address_space(3))) void*)l, 16, 0, 0);
}

// ---- block reductions (256 threads = 4 waves) ----
__device__ inline float blockSum256(float v, float* red) {
    #pragma unroll
    for (int o = 32; o > 0; o >>= 1) v += __shfl_down(v, o);
    int t = threadIdx.x;
    if ((t & 63) == 0) red[t >> 6] = v;
    __syncthreads();
    float r = red[0] + red[1] + red[2] + red[3];
    __syncthreads();
    return r;
}
__device__ inline float blockMax256(float v, float* red) {
    #pragma unroll
    for (int o = 32; o > 0; o >>= 1) v = fmaxf(v, __shfl_down(v, o));
    int t = threadIdx.x;
    if ((t & 63) == 0) red[t >> 6] = v;
    __syncthreads();
    float r = fmaxf(fmaxf(red[0], red[1]), fmaxf(red[2], red[3]));
    __syncthreads();
    return r;
}

// ---- fp32 -> bf16 weight conversion + optional stat zeroing ----
struct Cvt4 {
    const float* s[4];
    unsigned short* d[4];
    long n[4];
    float* z32;           // if non-null: zero 32 floats (IN stats accumulator)
};
__global__ __launch_bounds__(256)
void cvt_kernel(Cvt4 a) {
    if (a.z32 && blockIdx.x == 0 && threadIdx.x < 32) a.z32[threadIdx.x] = 0.f;
    long tid = (long)blockIdx.x * 256 + threadIdx.x;
    long stride = (long)gridDim.x * 256;
    for (int g = 0; g < 4; g++) {
        const float* s = a.s[g];
        if (!s) continue;
        unsigned short* d = a.d[g];
        long n = a.n[g];
        for (long i = tid * 4; i < n; i += stride * 4) {
            float4 v = *(const float4*)(s + i);
            *(ushort4*)(d + i) = make_ushort4(f2b(v.x), f2b(v.y), f2b(v.z), f2b(v.w));
        }
    }
}

// ==== mfma4: 128x128 tile, 4 waves (2Mx2N), BK=64, 2 phases per K-tile ====
// REQUIRES K >= 128, K % 8 == 0, Mpad/Npad % 128 == 0 with all rows/cols
// < Mpad/Npad READABLE (pads may be garbage; stores masked by M/N).
// XCD-chunked bijective remap (m204): block orig -> wgid so each XCD owns a
// contiguous m-major chunk -> A-panel L2 residency per XCD.
// LDS per operand: [2 slots][2 k-halves][128 rows][32 shorts]; 64 KB, 2 blk/CU.
// Swizzle hash h(r)=(r>>1)&3 (R13-proven, 0 conflicts), both-sides.
template <class CT, class RT, bool TO>
__global__ __launch_bounds__(256, 2)
void mfma4(const bf16* __restrict__ A, long Ah, long Ab, int lda,
           const bf16* __restrict__ B, long Bh, long Bb, int ldb,
           CT* __restrict__ Cp, long Ch, long Cb, int ldc,
           const float* __restrict__ bias, const RT* __restrict__ res,
           int M, int N, int K, int Mpad, int Npad, float alpha, int dogelu,
           float* __restrict__ stat) {
    __shared__ short Asl[2][2][128][32];
    __shared__ short Bsl[2][2][128][32];
    // ---- XCD-chunked bijective block remap ----
    int gx = gridDim.x, gy = gridDim.y;
    int nxy = gx * gy;
    int nwg = nxy * gridDim.z;
    int orig = ((int)blockIdx.z * gy + (int)blockIdx.y) * gx + (int)blockIdx.x;
    int q = nwg >> 3, r8 = nwg & 7;
    int xcd = orig & 7, pos = orig >> 3;
    int wgid = (xcd < r8 ? xcd * (q + 1) : r8 * (q + 1) + (xcd - r8) * q) + pos;
    int bz = wgid / nxy;
    int rem = wgid - bz * nxy;
    int by = rem / gx, bx = rem - by * gx;

    int z = bz;
    A += (long)(z & 3) * Ah + (long)(z >> 2) * Ab;
    B += (long)(z & 3) * Bh + (long)(z >> 2) * Bb;
    Cp += (long)(z & 3) * Ch + (long)(z >> 2) * Cb;
    int m0 = by * 128, n0 = bx * 128;
    int t = threadIdx.x, lane = t & 63, wv = t >> 6;   // wv 0..3
    int col = lane & 15, quad = lane >> 4;
    int wm = wv >> 1, wn = wv & 1;                     // 2(M) x 2(N)
    f32x4 acc[4][4];
    #pragma unroll
    for (int i = 0; i < 4; i++)
        #pragma unroll
        for (int j = 0; j < 4; j++) acc[i][j] = (f32x4){0.f, 0.f, 0.f, 0.f};

    const bool fA = (m0 + 128 <= Mpad);
    const bool fB = (n0 + 128 <= Npad);
    int srow = lane >> 2;
    int scol = ((lane & 3) ^ ((lane >> 3) & 3)) << 3;
    int rslot = (quad ^ ((col >> 1) & 3)) << 3;

    auto stageA = [&](int s2, int kt, int kh) {
        int k0 = kt * 64 + kh * 32;
        if (fA && k0 + 32 <= K) {
            #pragma unroll
            for (int r = 0; r < 2; r++) {
                int R0 = (r * 4 + wv) * 16;
                cp16(A + (long)(m0 + R0 + srow) * lda + k0 + scol,
                     &Asl[s2][kh][R0][0]);
            }
        } else {
            #pragma unroll
            for (int r = 0; r < 2; r++) {
                int idx = r * 256 + t;
                int row = idx >> 2, sl = idx & 3;
                int f2 = (row >> 1) & 3;
                short8 v = {};
                if (m0 + row < M && k0 + sl * 8 < K)   // K%8==0 at all call sites
                    v = *(const short8*)(A + (long)(m0 + row) * lda + k0 + sl * 8);
                *(short8*)&Asl[s2][kh][row][(sl ^ f2) * 8] = v;
            }
            asm volatile("s_waitcnt lgkmcnt(0)" ::: "memory");
        }
    };
    auto stageB = [&](int s2, int kt, int kh) {
        int k0 = kt * 64 + kh * 32;
        if (fB && k0 + 32 <= K) {
            #pragma unroll
            for (int r = 0; r < 2; r++) {
                int R0 = (r * 4 + wv) * 16;
                cp16(B + (long)(n0 + R0 + srow) * ldb + k0 + scol,
                     &Bsl[s2][kh][R0][0]);
            }
        } else {
            #pragma unroll
            for (int r = 0; r < 2; r++) {
                int idx = r * 256 + t;
                int row = idx >> 2, sl = idx & 3;
                int f2 = (row >> 1) & 3;
                short8 v = {};
                if (n0 + row < N && k0 + sl * 8 < K)
                    v = *(const short8*)(B + (long)(n0 + row) * ldb + k0 + sl * 8);
                *(short8*)&Bsl[s2][kh][row][(sl ^ f2) * 8] = v;
            }
            asm volatile("s_waitcnt lgkmcnt(0)" ::: "memory");
        }
    };

    int nk = (K + 63) >> 6;
    stageA(0, 0, 0); stageB(0, 0, 0); stageA(0, 0, 1); stageB(0, 0, 1);
    __syncthreads();

    for (int kt = 0; kt < nk; kt++) {
        int cur = kt & 1, nxt = cur ^ 1;
        bool st = (kt + 1 < nk);
        short8 af[4], bf4[4];
        // ---------- phase 0: k-half 0 ----------
        #pragma unroll
        for (int mi = 0; mi < 4; mi++)
            af[mi] = *(const short8*)&Asl[cur][0][wm * 64 + mi * 16 + col][rslot];
        #pragma unroll
        for (int ni = 0; ni < 4; ni++)
            bf4[ni] = *(const short8*)&Bsl[cur][0][wn * 64 + ni * 16 + col][rslot];
        if (st) { stageA(nxt, kt + 1, 0); stageB(nxt, kt + 1, 0); }
        __builtin_amdgcn_s_barrier();
        asm volatile("s_waitcnt lgkmcnt(0)" ::: "memory");
        __builtin_amdgcn_sched_barrier(0);
        __builtin_amdgcn_s_setprio(1);
        #pragma unroll
        for (int mi = 0; mi < 4; mi++)
            #pragma unroll
            for (int ni = 0; ni < 4; ni++)
                acc[mi][ni] = __builtin_amdgcn_mfma_f32_16x16x32_bf16(
                    af[mi], bf4[ni], acc[mi][ni], 0, 0, 0);
        __builtin_amdgcn_s_setprio(0);
        if (st) {
            if (fA && fB)      asm volatile("s_waitcnt vmcnt(4)" ::: "memory");
            else if (fA || fB) asm volatile("s_waitcnt vmcnt(2)" ::: "memory");
        } else {
            asm volatile("s_waitcnt vmcnt(0)" ::: "memory");
        }
        __builtin_amdgcn_s_barrier();
        // ---------- phase 1: k-half 1 ----------
        #pragma unroll
        for (int mi = 0; mi < 4; mi++)
            af[mi] = *(const short8*)&Asl[cur][1][wm * 64 + mi * 16 + col][rslot];
        #pragma unroll
        for (int ni = 0; ni < 4; ni++)
            bf4[ni] = *(const short8*)&Bsl[cur][1][wn * 64 + ni * 16 + col][rslot];
        if (st) { stageA(nxt, kt + 1, 1); stageB(nxt, kt + 1, 1); }
        __builtin_amdgcn_s_barrier();
        asm volatile("s_waitcnt lgkmcnt(0)" ::: "memory");
        __builtin_amdgcn_sched_barrier(0);
        __builtin_amdgcn_s_setprio(1);
        #pragma unroll
        for (int mi = 0; mi < 4; mi++)
            #pragma unroll
            for (int ni = 0; ni < 4; ni++)
                acc[mi][ni] = __builtin_amdgcn_mfma_f32_16x16x32_bf16(
                    af[mi], bf4[ni], acc[mi][ni], 0, 0, 0);
        __builtin_amdgcn_s_setprio(0);
        if (st) {
            if (fA && fB)      asm volatile("s_waitcnt vmcnt(4)" ::: "memory");
            else if (fA || fB) asm volatile("s_waitcnt vmcnt(2)" ::: "memory");
        }
        __builtin_amdgcn_s_barrier();
    }
    // epilogue — C/D layout: col=lane&15, row=quad*4+reg [m89/m91]
    float psum = 0.f, psq = 0.f;
    #pragma unroll
    for (int mi = 0; mi < 4; mi++) {
        int gmB = m0 + wm * 64 + mi * 16 + quad * 4;
        #pragma unroll
        for (int ni = 0; ni < 4; ni++) {
            int gn = n0 + wn * 64 + ni * 16 + col;
            if constexpr (TO) {
                if (gmB < M && gn < N) {
                    ushort4 w = make_ushort4(f2b(acc[mi][ni][0] * alpha),
                                             f2b(acc[mi][ni][1] * alpha),
                                             f2b(acc[mi][ni][2] * alpha),
                                             f2b(acc[mi][ni][3] * alpha));
                    *(ushort4*)((unsigned short*)Cp + (long)gn * ldc + gmB) = w;
                }
            } else {
                if (gn < N) {
                    float bz2 = bias ? bias[gn] : 0.f;
                    #pragma unroll
                    for (int r = 0; r < 4; r++) {
                        int gm = gmB + r;
                        if (gm < M) {
                            float v = acc[mi][ni][r] * alpha + bz2;
                            if (dogelu) v = 0.5f * v * (1.f + erff(v * 0.70710678118f));
                            if (res) v += ld1f(res + (long)gm * ldc + gn);
                            st1(Cp + (long)gm * ldc + gn, v);
                            psum += v; psq += v * v;
                        }
                    }
                }
            }
        }
    }
    if (stat) {   // fused InstanceNorm partial stats, one atomicAdd pair/block
        __syncthreads();
        #pragma unroll
        for (int o = 32; o > 0; o >>= 1) {
            psum += __shfl_down(psum, o);
            psq  += __shfl_down(psq, o);
        }
        float* red = (float*)Asl;
        if ((t & 63) == 0) { red[wv] = psum; red[4 + wv] = psq; }
        __syncthreads();
        if (t == 0) {
            atomicAdd(&stat[2 * z],     red[0] + red[1] + red[2] + red[3]);
            atomicAdd(&stat[2 * z + 1], red[4] + red[5] + red[6] + red[7]);
        }
    }
}

// ==== mfma2 (R13 form) + optional fused stats — C=64 branch only ====
template <int TM, int TN, class CT, class RT, bool TO>
__global__ __launch_bounds__(256)
void mfma2(const bf16* __restrict__ A, long Ah, long Ab, int lda,
           const bf16* __restrict__ B, long Bh, long Bb, int ldb,
           CT* __restrict__ Cp, long Ch, long Cb, int ldc,
           const float* __restrict__ bias, const RT* __restrict__ res,
           int M, int N, int K, float alpha, int dogelu,
           float* __restrict__ stat) {
    constexpr int MI = TM / 32, NI = TN / 32;
    __shared__ short As[2][TM * 32];
    __shared__ short Bs[2][TN * 32];
    int z = blockIdx.z;
    A += (long)(z & 3) * Ah + (long)(z >> 2) * Ab;
    B += (long)(z & 3) * Bh + (long)(z >> 2) * Bb;
    Cp += (long)(z & 3) * Ch + (long)(z >> 2) * Cb;
    int m0 = blockIdx.y * TM, n0 = blockIdx.x * TN;
    int t = threadIdx.x, lane = t & 63, wv = t >> 6;
    int col = lane & 15, quad = lane >> 4;
    int wm = wv >> 1, wn = wv & 1;
    f32x4 acc[MI][NI];
    #pragma unroll
    for (int i = 0; i < MI; i++)
        #pragma unroll
        for (int j = 0; j < NI; j++) acc[i][j] = (f32x4){0.f, 0.f, 0.f, 0.f};

    const bool fastblk = (m0 + TM <= M) && (n0 + TN <= N);
    int lrow = lane >> 2;
    int lcol = ((lane & 3) ^ ((lane >> 3) & 3)) << 3;
    int sr = t >> 2;
    int swz = ((t & 3) ^ ((t >> 3) & 3)) << 3;
    int sdst = (t & 3) << 3;
    int rdslot = (quad ^ ((col >> 1) & 3)) << 3;

    auto stage = [&](int b, int k0) {
        if (fastblk && (k0 + 32 <= K)) {
            #pragma unroll
            for (int u = 0; u < TM / 64; u++) {
                int c = wv + 4 * u;
                int r = c * 16 + lrow;
                cp16(A + (long)(m0 + r) * lda + k0 + lcol, &As[b][c * 512]);
            }
            #pragma unroll
            for (int u = 0; u < TN / 64; u++) {
                int c = wv + 4 * u;
                int r = c * 16 + lrow;
                cp16(B + (long)(n0 + r) * ldb + k0 + lcol, &Bs[b][c * 512]);
            }
        } else {
            #pragma unroll
            for (int u = 0; u < TM / 64; u++) {
                int r = sr + u * 64;
                float4 v = make_float4(0.f, 0.f, 0.f, 0.f);
                if (m0 + r < M && k0 + swz < K)
                    v = *(const float4*)(A + (long)(m0 + r) * lda + k0 + swz);
                *(float4*)&As[b][r * 32 + sdst] = v;
            }
            #pragma unroll
            for (int u = 0; u < TN / 64; u++) {
                int r = sr + u * 64;
                float4 v = make_float4(0.f, 0.f, 0.f, 0.f);
                if (n0 + r < N && k0 + swz < K)
                    v = *(const float4*)(B + (long)(n0 + r) * ldb + k0 + swz);
                *(float4*)&Bs[b][r * 32 + sdst] = v;
            }
        }
    };

    int nk = (K + 31) >> 5;
    stage(0, 0);
    __syncthreads();
    int cur = 0;
    for (int s = 0; s < nk; s++) {
        if (s + 1 < nk) stage(cur ^ 1, (s + 1) * 32);
        short8 af[MI], bfr[NI];
        #pragma unroll
        for (int mi = 0; mi < MI; mi++)
            af[mi] = *(const short8*)&As[cur][(wm * (TM / 2) + mi * 16 + col) * 32 + rdslot];
        #pragma unroll
        for (int ni = 0; ni < NI; ni++)
            bfr[ni] = *(const short8*)&Bs[cur][(wn * (TN / 2) + ni * 16 + col) * 32 + rdslot];
        #pragma unroll
        for (int mi = 0; mi < MI; mi++)
            #pragma unroll
            for (int ni = 0; ni < NI; ni++)
                acc[mi][ni] = __builtin_amdgcn_mfma_f32_16x16x32_bf16(
                    af[mi], bfr[ni], acc[mi][ni], 0, 0, 0);
        if (s + 1 < nk) __syncthreads();
        cur ^= 1;
    }
    float psum = 0.f, psq = 0.f;
    #pragma unroll
    for (int mi = 0; mi < MI; mi++) {
        int gmB = m0 + wm * (TM / 2) + mi * 16 + quad * 4;
        #pragma unroll
        for (int ni = 0; ni < NI; ni++) {
            int gn = n0 + wn * (TN / 2) + ni * 16 + col;
            if constexpr (TO) {
                if (gmB < M && gn < N) {
                    ushort4 w = make_ushort4(f2b(acc[mi][ni][0] * alpha),
                                             f2b(acc[mi][ni][1] * alpha),
                                             f2b(acc[mi][ni][2] * alpha),
                                             f2b(acc[mi][ni][3] * alpha));
                    *(ushort4*)((unsigned short*)Cp + (long)gn * ldc + gmB) = w;
                }
            } else {
                if (gn < N) {
                    float bz = bias ? bias[gn] : 0.f;
                    #pragma unroll
                    for (int r = 0; r < 4; r++) {
                        int gm = gmB + r;
                        if (gm < M) {
                            float v = acc[mi][ni][r] * alpha + bz;
                            if (dogelu) v = 0.5f * v * (1.f + erff(v * 0.70710678118f));
                            if (res) v += ld1f(res + (long)gm * ldc + gn);
                            st1(Cp + (long)gm * ldc + gn, v);
                            psum += v; psq += v * v;
                        }
                    }
                }
            }
        }
    }
    if (stat) {
        __syncthreads();
        #pragma unroll
        for (int o = 32; o > 0; o >>= 1) {
            psum += __shfl_down(psum, o);
            psq  += __shfl_down(psq, o);
        }
        float* red = (float*)As;
        if ((t & 63) == 0) { red[wv] = psum; red[4 + wv] = psq; }
        __syncthreads();
        if (t == 0) {
            atomicAdd(&stat[2 * z],     red[0] + red[1] + red[2] + red[3]);
            atomicAdd(&stat[2 * z + 1], red[4] + red[5] + red[6] + red[7]);
        }
    }
}

// ---- merged LayerNorms: concat-LN (ea) + 4 branch first-LNs, one emb read ----
struct LNA {
    const float* e[4];
    const float* ag[4];
    const float* ab[4];
    const float* cg;
    const float* cbb;
    bf16* y[4];
    bf16* ea;
};
__global__ __launch_bounds__(256)
void ln_all_kernel(LNA a) {
    __shared__ float x[960];
    __shared__ float red[4];
    long row = blockIdx.x;
    int t = threadIdx.x;
    const int off[5] = {0, 64, 192, 448, 960};
    {
        const float* p1 = a.e[0] + row * 64;
        const float* p2 = a.e[1] + row * 128;
        const float* p3 = a.e[2] + row * 256;
        const float* p4 = a.e[3] + row * 512;
        if (t < 64) x[t] = p1[t];
        for (int i = t; i < 128; i += 256) x[64 + i]  = p2[i];
        for (int i = t; i < 256; i += 256) x[192 + i] = p3[i];
        for (int i = t; i < 512; i += 256) x[448 + i] = p4[i];
    }
    __syncthreads();
    float ssum[4], ssq[4];
    #pragma unroll
    for (int br = 0; br < 4; br++) {
        float s = 0.f, q = 0.f;
        for (int i = off[br] + t; i < off[br + 1]; i += 256) {
            float v = x[i]; s += v; q += v * v;
        }
        ssum[br] = blockSum256(s, red);
        ssq[br]  = blockSum256(q, red);
    }
    float S1 = ssum[0] + ssum[1] + ssum[2] + ssum[3];
    float S2 = ssq[0] + ssq[1] + ssq[2] + ssq[3];
    float muA = S1 * (1.f / 960.f);
    float rA = rsqrtf(S2 * (1.f / 960.f) - muA * muA + 1e-6f);
    for (int i = t; i < 960; i += 256)
        st1(a.ea + row * 960 + i, (x[i] - muA) * rA * a.cg[i] + a.cbb[i]);
    #pragma unroll
    for (int br = 0; br < 4; br++) {
        int C = off[br + 1] - off[br];
        float mu = ssum[br] / C;
        float rr = rsqrtf(ssq[br] / C - mu * mu + 1e-6f);
        const float* g = a.ag[br];
        const float* b = a.ab[br];
        bf16* y = a.y[br] + row * C;
        for (int i = t; i < C; i += 256)
            st1(y + i, (x[off[br] + i] - mu) * rr * g[i] + b[i]);
    }
}

// ---- row LayerNorm (bf16 in) -> bf16 ----
__global__ __launch_bounds__(256)
void ln_rows_kernel(const bf16* __restrict__ X, const float* __restrict__ g,
                    const float* __restrict__ b, bf16* __restrict__ Y, int C) {
    __shared__ float x[512];
    __shared__ float red[4];
    long row = blockIdx.x;
    int t = threadIdx.x;
    const bf16* xr = X + row * C;
    float s = 0.f, q = 0.f;
    for (int i = t; i < C; i += 256) { float v = ld1f(xr + i); x[i] = v; s += v; q += v * v; }
    float S1 = blockSum256(s, red), S2 = blockSum256(q, red);
    float mu = S1 / C;
    float r = rsqrtf(S2 / C - mu * mu + 1e-6f);
    for (int i = t; i < C; i += 256)
        st1(Y + row * C + i, (x[i] - mu) * r * g[i] + b[i]);
}

// ---- ctx head-sum: ctx[i] = 0.25*sum_h tmp[h][i] ----
__global__ __launch_bounds__(256)
void ctx_sum_kernel(const bf16* __restrict__ tmp, bf16* __restrict__ ctx, long NTC) {
    long i = ((long)blockIdx.x * 256 + threadIdx.x) * 4;
    float4 a = ld4f(tmp + i);
    float4 b = ld4f(tmp + NTC + i);
    float4 c = ld4f(tmp + 2 * NTC + i);
    float4 d = ld4f(tmp + 3 * NTC + i);
    ushort4 o = make_ushort4(f2b((a.x + b.x + c.x + d.x) * 0.25f),
                             f2b((a.y + b.y + c.y + d.y) * 0.25f),
                             f2b((a.z + b.z + c.z + d.z) * 0.25f),
                             f2b((a.w + b.w + c.w + d.w) * 0.25f));
    *(ushort4*)(ctx + i) = o;
}

// ---- softmax over last dim (960) of S2[b][C][4*960]; rstd from fused stats ----
__global__ __launch_bounds__(256)
void softmax_kernel(bf16* __restrict__ S, const float* __restrict__ stat, int C) {
    __shared__ float x[960];
    __shared__ float red[4];
    long r = blockIdx.x;
    int t = threadIdx.x;
    int z = (int)(r / C);           // stats z: z&3=h, z>>2=b (matches S-GEMM)
    int d = (int)(r % C);
    float n = 960.f * (float)C;
    float s0 = stat[2 * z], q0 = stat[2 * z + 1];
    float mu = s0 / n;
    float rs = rsqrtf(q0 / n - mu * mu + 1e-5f);
    int h = z & 3, b = z >> 2;
    bf16* row = S + (long)b * C * 3840 + (long)d * 3840 + h * 960;
    float mx = -3.4e38f;
    for (int i = t; i < 960; i += 256) {
        float v = ld1f(row + i) * rs; x[i] = v; mx = fmaxf(mx, v);
    }
    float M = blockMax256(mx, red);
    float s = 0.f;
    for (int i = t; i < 960; i += 256) { float e = __expf(x[i] - M); x[i] = e; s += e; }
    float Ssum = blockSum256(s, red);
    float inv = 1.f / Ssum;
    for (int i = t; i < 960; i += 256) st1(row + i, x[i] * inv);
}

extern "C" void kernel_launch(void* const* d_in, const int* in_sizes, int n_in,
                              void* d_out, int out_size, void* d_ws, size_t ws_size,
                              hipStream_t stream) {
    (void)in_sizes; (void)n_in; (void)out_size; (void)ws_size;
    const int Cs[4] = {64, 128, 256, 512};
    const float *emb[4], *ang[4], *anb[4], *Wq[4], *Wo[4], *fng[4], *fnb[4], *w1[4], *b1[4], *w2[4], *b2[4];
    for (int i = 0; i < 4; i++) {
        const int base = i * 11;
        emb[i] = (const float*)d_in[base + 0];
        ang[i] = (const float*)d_in[base + 1];
        anb[i] = (const float*)d_in[base + 2];
        Wq[i]  = (const float*)d_in[base + 3];
        Wo[i]  = (const float*)d_in[base + 4];
        fng[i] = (const float*)d_in[base + 5];
        fnb[i] = (const float*)d_in[base + 6];
        w1[i]  = (const float*)d_in[base + 7];
        b1[i]  = (const float*)d_in[base + 8];
        w2[i]  = (const float*)d_in[base + 9];
        b2[i]  = (const float*)d_in[base + 10];
    }
    const float* anAg = (const float*)d_in[44];
    const float* anAb = (const float*)d_in[45];
    const float* Wk   = (const float*)d_in[46];
    const float* Wv   = (const float*)d_in[47];

    const int NT = 3136;
    char* wsb = (char*)d_ws;
    bf16*   ea    = (bf16*)(wsb);                    // [3136,960] (+pad reads OK)
    bf16*   KT    = (bf16*)(wsb + 6021120);          // [3840][3136] = [4][960][3136]
    bf16*   Vb2   = (bf16*)(wsb + 30105600);         // [3136][3840] head-concat V
    bf16*   Qb    = (bf16*)(wsb + 54190080);         // QT / per-head tmp / hid
    bf16*   Sb    = (bf16*)(wsb + 67035136);         // S2 [b][C][3840]; wk/wv early
    bf16*   cxall = (bf16*)(wsb + 82763776);         // first-LN out, all branches
    bf16*   cxb   = (bf16*)(wsb + 88784896);         // ctx / post-res LN
    bf16*   xb    = (bf16*)(wsb + 91996160);         // residual
    bf16*   wtb   = (bf16*)(wsb + 95207424);         // per-branch weights, reused
    float*  statb = (float*)(wsb + 102023168);       // [32] IN sum/sumsq per z

    bf16* wkb = Sb;                 // Sb region free until branch-0 scores
    bf16* wvb = Sb + 3686400;       // wkb/wvb contiguous: [3840][960] each
    const long cxoff[4] = {0, 64L * NT, 192L * NT, 448L * NT};

    float* out = (float*)d_out;
    const long ooff[4] = {0, 200704, 602112, 1404928};
    const float scale = 0.03227486121f;  // 1/sqrt(960)

    {
        Cvt4 a;
        a.s[0] = Wk; a.d[0] = (unsigned short*)wkb; a.n[0] = 3686400;
        a.s[1] = Wv; a.d[1] = (unsigned short*)wvb; a.n[1] = 3686400;
        a.s[2] = nullptr; a.s[3] = nullptr; a.d[2] = a.d[3] = nullptr; a.n[2] = a.n[3] = 0;
        a.z32 = nullptr;
        cvt_kernel<<<512, 256, 0, stream>>>(a);
    }
    {
        LNA a;
        for (int i = 0; i < 4; i++) {
            a.e[i] = emb[i]; a.ag[i] = ang[i]; a.ab[i] = anb[i];
            a.y[i] = cxall + cxoff[i];
        }
        a.cg = anAg; a.cbb = anAb; a.ea = ea;
        ln_all_kernel<<<3136, 256, 0, stream>>>(a);
    }
    // K-proj: KT[h*960+j][n] = (ea @ Wk_all^T)^T — z=1, N=3840, Mpad 3328
    mfma4<bf16, float, true><<<dim3(30, 26, 1), 256, 0, stream>>>(
        ea, 0, 0, 960, wkb, 0, 0, 960, KT, 0, 0, NT,
        nullptr, (const float*)nullptr, NT, 3840, 960, 3328, 3840, 1.f, 0, nullptr);
    // V-proj: Vb2[n][h*960+j] — z=1, N=3840, Mpad 3328
    mfma4<bf16, float, false><<<dim3(30, 26, 1), 256, 0, stream>>>(
        ea, 0, 0, 960, wvb, 0, 0, 960, Vb2, 0, 0, 3840,
        nullptr, (const float*)nullptr, NT, 3840, 960, 3328, 3840, 1.f, 0, nullptr);

    for (int i = 0; i < 4; i++) {
        const int C = Cs[i];
        const long C2 = (long)C * C;
        bf16* wqb = wtb;
        bf16* wob = wtb + 4 * C2;
        bf16* w1b = wtb + 5 * C2;
        bf16* w2b = wtb + 9 * C2;
        {
            Cvt4 a;
            a.s[0] = Wq[i]; a.d[0] = (unsigned short*)wqb; a.n[0] = 4 * C2;
            a.s[1] = Wo[i]; a.d[1] = (unsigned short*)wob; a.n[1] = C2;
            a.s[2] = w1[i]; a.d[2] = (unsigned short*)w1b; a.n[2] = 4 * C2;
            a.s[3] = w2[i]; a.d[3] = (unsigned short*)w2b; a.n[3] = 4 * C2;
            a.z32 = statb;                 // zero IN stats for this branch
            cvt_kernel<<<512, 256, 0, stream>>>(a);
        }
        if (C >= 128) {
            // QT[h] = (cx @ Wq[h]^T)^T — Mpad 3328
            mfma4<bf16, float, true><<<dim3(C / 128, 26, 4), 256, 0, stream>>>(
                cxall + cxoff[i], 0, 0, C, wqb, C2, 0, C, Qb, (long)C * NT, 0, NT,
                nullptr, (const float*)nullptr, NT, C, C, 3328, C, 1.f, 0, nullptr);
            // S2[b][d][h*960+j] = scale * QT @ KT^T  (K=784 tail) — Npad 1024
            mfma4<bf16, float, false><<<dim3(8, C / 128, 16), 256, 0, stream>>>(
                Qb, (long)C * NT, 784, NT, KT, 3010560, 784, NT,
                Sb, 960, (long)C * 3840, 3840,
                nullptr, (const float*)nullptr, C, 960, 784, C, 1024, scale, 0, statb);
        } else {
            mfma2<64, 64, bf16, float, true><<<dim3(1, 49, 4), 256, 0, stream>>>(
                cxall + cxoff[i], 0, 0, C, wqb, C2, 0, C, Qb, (long)C * NT, 0, NT,
                nullptr, (const float*)nullptr, NT, C, C, 1.f, 0, nullptr);
            mfma2<64, 64, bf16, float, false><<<dim3(15, 1, 16), 256, 0, stream>>>(
                Qb, (long)C * NT, 784, NT, KT, 3010560, 784, NT,
                Sb, 960, (long)C * 3840, 3840,
                nullptr, (const float*)nullptr, C, 960, 784, scale, 0, statb);
        }
        softmax_kernel<<<16 * C, 256, 0, stream>>>(Sb, statb, C);
        // tmp[h] = V-slab @ S[z]^T  (per-head K=960) -> ctx_sum — Mpad 896
        if (C >= 128)
            mfma4<bf16, float, false><<<dim3(C / 128, 7, 16), 256, 0, stream>>>(
                Vb2, 960, 784L * 3840, 3840, Sb, 960, (long)C * 3840, 3840,
                Qb, (long)NT * C, 784L * C, C,
                nullptr, (const float*)nullptr, 784, C, 960, 896, C, 1.f, 0, nullptr);
        else
            mfma2<64, 64, bf16, float, false><<<dim3(1, 13, 16), 256, 0, stream>>>(
                Vb2, 960, 784L * 3840, 3840, Sb, 960, (long)C * 3840, 3840,
                Qb, (long)NT * C, 784L * C, C,
                nullptr, (const float*)nullptr, 784, C, 960, 1.f, 0, nullptr);
        ctx_sum_kernel<<<(int)(((long)NT * C) / 1024), 256, 0, stream>>>(
            Qb, cxb, (long)NT * C);
        // x = emb + ctx @ Wo^T  -> bf16 — Mpad 3328
        if (C >= 128)
            mfma4<bf16, float, false><<<dim3(C / 128, 26, 1), 256, 0, stream>>>(
                cxb, 0, 0, C, wob, 0, 0, C, xb, 0, 0, C,
                nullptr, emb[i], NT, C, C, 3328, C, 1.f, 0, nullptr);
        else
            mfma2<64, 64, bf16, float, false><<<dim3(1, 49, 1), 256, 0, stream>>>(
                cxb, 0, 0, C, wob, 0, 0, C, xb, 0, 0, C,
                nullptr, emb[i], NT, C, C, 1.f, 0, nullptr);
        ln_rows_kernel<<<NT, 256, 0, stream>>>(xb, fng[i], fnb[i], cxb, C);
        // hid = gelu(lnx @ w1^T + b1) -> bf16 — Mpad 3328
        if (C >= 128)
            mfma4<bf16, float, false><<<dim3(4 * C / 128, 26, 1), 256, 0, stream>>>(
                cxb, 0, 0, C, w1b, 0, 0, C, Qb, 0, 0, 4 * C,
                b1[i], (const float*)nullptr, NT, 4 * C, C, 3328, 4 * C, 1.f, 1, nullptr);
        else
            mfma2<64, 64, bf16, float, false><<<dim3(4, 49, 1), 256, 0, stream>>>(
                cxb, 0, 0, C, w1b, 0, 0, C, Qb, 0, 0, 4 * C,
                b1[i], (const float*)nullptr, NT, 4 * C, C, 1.f, 1, nullptr);
        // out = x + hid @ w2^T + b2  (fp32 store to d_out) — Mpad 3328
        if (C >= 128)
            mfma4<float, bf16, false><<<dim3(C / 128, 26, 1), 256, 0, stream>>>(
                Qb, 0, 0, 4 * C, w2b, 0, 0, 4 * C, out + ooff[i], 0, 0, C,
                b2[i], xb, NT, C, 4 * C, 3328, C, 1.f, 0, nullptr);
        else
            mfma2<64, 64, float, bf16, false><<<dim3(1, 49, 1), 256, 0, stream>>>(
                Qb, 0, 0, 4 * C, w2b, 0, 0, 4 * C, out + ooff[i], 0, 0, C,
                b2[i], xb, NT, C, 4 * C, 1.f, 0, nullptr);
    }
}